// Round 13
// baseline (467.834 us; speedup 1.0000x reference)
//
#include <hip/hip_runtime.h>

// Problem constants (fixed by setup_inputs)
#define NNODES 8000
#define NEDGES 192000
#define NREL   65
#define RP     66      // +1 pseudo-relation for the root/self term
#define HDIM   256
#define FDIM   64
#define NGRAPH 128
#define MDIM   64
#define TILE_M 256
#define MAXT   856     // >= E/256 + 65 + 32 = 847; == 8*107 for XCD swizzle
#define EPTOT  (NEDGES + NNODES)

typedef _Float16 half8 __attribute__((ext_vector_type(8)));
typedef _Float16 half4 __attribute__((ext_vector_type(4)));
typedef float    f32x4 __attribute__((ext_vector_type(4)));
// clang vector type (NOT HIP's struct uint4) — required by __builtin_nontemporal_*
typedef unsigned int u32x4 __attribute__((ext_vector_type(4)));

// ---------------- setup kernels ----------------

__global__ void count_kernel(const int* __restrict__ ei, const int* __restrict__ et,
                             int* __restrict__ cnt_rn, int* __restrict__ type_cnt,
                             int* __restrict__ ddeg) {
    __shared__ int lbin[NREL];
    int tid = threadIdx.x;
    if (tid < NREL) lbin[tid] = 0;
    __syncthreads();
    int e = blockIdx.x * 256 + tid;
    if (e < NEDGES) {
        int t = et[e];
        int d = ei[NEDGES + e];
        atomicAdd(&lbin[t], 1);
        atomicAdd(&cnt_rn[t * NNODES + d], 1);
        atomicAdd(&ddeg[d], 1);
    }
    __syncthreads();
    if (tid < NREL && lbin[tid] > 0) atomicAdd(&type_cnt[tid], lbin[tid]);
}

// R13: scan_tiles (block 0) + dst_scan (block 1) merged — both depend only on
// count_kernel outputs; saves one serialized launch.
__global__ void scan2_kernel(const int* __restrict__ type_cnt, int* __restrict__ type_off,
                             int* __restrict__ tile_rel, int* __restrict__ tile_start,
                             int* __restrict__ tile_nrows,
                             const int* __restrict__ ddeg, int* __restrict__ dst_off) {
    if (blockIdx.x == 0) {
        // ---- tile scan ----
        __shared__ int s_off[RP + 1];
        __shared__ int s_toff[RP + 1];
        if (threadIdx.x == 0) {
            int off = 0, toff = 0;
            for (int r = 0; r < RP; r++) {
                int c = (r < NREL) ? type_cnt[r] : NNODES;
                s_off[r] = off; s_toff[r] = toff;
                off += c; toff += (c + TILE_M - 1) / TILE_M;
            }
            s_off[RP] = off; s_toff[RP] = toff;
            type_off[RP] = off;
        }
        __syncthreads();
        int r = threadIdx.x;
        if (r < RP) {
            type_off[r] = s_off[r];
            int c = s_off[r + 1] - s_off[r];
            int nt = (c + TILE_M - 1) / TILE_M;
            for (int i = 0; i < nt; i++) {
                int idx = s_toff[r] + i;
                tile_rel[idx]   = r;
                tile_start[idx] = s_off[r] + i * TILE_M;
                tile_nrows[idx] = min(TILE_M, c - i * TILE_M);
            }
        }
    } else {
        // ---- exclusive prefix scan of (ddeg[n]+1) -> dst_off ----
        __shared__ int part[256];
        int t = threadIdx.x;
        int base = t * 32;
        int s = 0;
        for (int i = 0; i < 32; i++) {
            int n = base + i;
            if (n < NNODES) s += ddeg[n] + 1;
        }
        part[t] = s;
        __syncthreads();
        if (t == 0) {
            int run = 0;
            for (int i = 0; i < 256; i++) { int tmp = part[i]; part[i] = run; run += tmp; }
            dst_off[NNODES] = run;   // == EPTOT
        }
        __syncthreads();
        int run = part[t];
        for (int i = 0; i < 32; i++) {
            int n = base + i;
            if (n < NNODES) { dst_off[n] = run; run += ddeg[n] + 1; }
        }
    }
}

// Relation-sorted slot p (block-aggregated rank) + dst-sorted output slot q.
__global__ void scatter_kernel(const int* __restrict__ ei, const int* __restrict__ et,
                               const int* __restrict__ cnt_rn, const int* __restrict__ type_off,
                               int* __restrict__ type_cur,
                               const int* __restrict__ dst_off, int* __restrict__ dst_cur,
                               int* __restrict__ esrc, int* __restrict__ eq,
                               float* __restrict__ escale) {
    __shared__ int lbin[NREL];
    __shared__ int gbase[NREL];
    int tid = threadIdx.x;
    if (tid < NREL) lbin[tid] = 0;
    __syncthreads();
    int i = blockIdx.x * 256 + tid;
    int t = 0, lrank = 0;
    bool is_edge = (i < NEDGES);
    if (is_edge) {
        t = et[i];
        lrank = atomicAdd(&lbin[t], 1);
    }
    __syncthreads();
    if (tid < NREL && lbin[tid] > 0) gbase[tid] = atomicAdd(&type_cur[tid], lbin[tid]);
    __syncthreads();
    if (is_edge) {
        int d = ei[NEDGES + i];
        int p = type_off[t] + gbase[t] + lrank;
        int q = dst_off[d] + atomicAdd(&dst_cur[d], 1);
        esrc[p] = ei[i];
        eq[p] = q;
        escale[p] = 1.0f / (float)cnt_rn[t * NNODES + d];
    } else if (i < EPTOT) {
        int n = i - NEDGES;
        int p = NEDGES + n;      // root pseudo-relation segment starts at E
        int q = dst_off[n] + atomicAdd(&dst_cur[n], 1);
        esrc[p] = n; eq[p] = q; escale[p] = 1.0f;
    }
}

// R13: convW x3 + conv_x merged into one flat-grid kernel (4 launches -> 1).
// convW: W [R][K][HDIM] fp32 (+ root [K][HDIM]) -> Wt [RP][HDIM][K] fp16.
__device__ __forceinline__ void convW_body(const float* __restrict__ W,
                                           const float* __restrict__ root,
                                           _Float16* __restrict__ Wt, int K, int b) {
    int nk = K / 32;
    int r   = b / (nk * 8);
    int rem = b % (nk * 8);
    int k0  = (rem / 8) * 32, n0 = (rem % 8) * 32;
    const float* src = (r < NREL) ? (W + (size_t)r * K * HDIM) : root;
    __shared__ float tile[32][33];
    int tj = threadIdx.x & 31, ti = threadIdx.x >> 5;
    #pragma unroll
    for (int s = 0; s < 4; s++) {
        int i = ti + s * 8;
        tile[i][tj] = src[(size_t)(k0 + i) * HDIM + n0 + tj];
    }
    __syncthreads();
    #pragma unroll
    for (int s = 0; s < 4; s++) {
        int i = ti + s * 8;
        Wt[((size_t)r * HDIM + (n0 + i)) * K + k0 + tj] = (_Float16)tile[tj][i];
    }
}

#define PREP_B1 (RP * (FDIM / 32) * 8)            // 1056
#define PREP_B2 (RP * (HDIM / 32) * 8)            // 4224
#define PREP_BX ((NNODES * FDIM) / 256)           // 2000
#define PREP_TOT (PREP_B1 + 2 * PREP_B2 + PREP_BX)

__global__ void prep_kernel(const float* __restrict__ W1, const float* __restrict__ root1,
                            const float* __restrict__ W2, const float* __restrict__ root2,
                            const float* __restrict__ W3, const float* __restrict__ root3,
                            const float* __restrict__ x,
                            _Float16* __restrict__ Wt1, _Float16* __restrict__ Wt2,
                            _Float16* __restrict__ Wt3, _Float16* __restrict__ x16) {
    int b = blockIdx.x;
    if (b < PREP_B1) {
        convW_body(W1, root1, Wt1, FDIM, b);
    } else if (b < PREP_B1 + PREP_B2) {
        convW_body(W2, root2, Wt2, HDIM, b - PREP_B1);
    } else if (b < PREP_B1 + 2 * PREP_B2) {
        convW_body(W3, root3, Wt3, HDIM, b - PREP_B1 - PREP_B2);
    } else {
        int i = (b - PREP_B1 - 2 * PREP_B2) * 256 + threadIdx.x;
        if (i < NNODES * FDIM) x16[i] = (_Float16)x[i];
    }
}

// ---------------- phase 1: Y16[q] = scale * (h[src] @ W_r) ----------------
// R12 kernel, UNCHANGED (66.5us K=256; tile-geometry axis saturated).
template <int K>
__global__ __launch_bounds__(512)
void edge_gemm_kernel(const _Float16* __restrict__ hin, const _Float16* __restrict__ Wt,
                      const int* __restrict__ esrc, const int* __restrict__ eq,
                      const float* __restrict__ escale,
                      const int* __restrict__ tile_rel, const int* __restrict__ tile_start,
                      const int* __restrict__ tile_nrows,
                      _Float16* __restrict__ Y) {
    // XCD swizzle: relation-sorted tiles colocate per XCD. Bijective: 8*107.
    int bid  = blockIdx.x;
    int tile = (bid & 7) * (MAXT / 8) + (bid >> 3);

    int nr = tile_nrows[tile];
    if (nr == 0) return;
    int r  = tile_rel[tile];
    int ts = tile_start[tile];

    constexpr int KH  = (K > 128) ? 128 : K;   // staged K per pass (128 / 64)
    constexpr int NST = K / KH;                // stages (2 / 1)
    constexpr int SO  = HDIM + 8;              // epilogue out stride = 264
    constexpr int AEL = TILE_M * KH;           // per-stage A tile (linear, unpadded)
    constexpr int OEL = 128 * SO;              // 128-row epilogue half = 33792
    constexpr int EL  = (NST * AEL > OEL) ? NST * AEL : OEL;
    __shared__ _Float16 sbuf[EL];              // A stage buffers, then epilogue
    __shared__ int   sq[TILE_M];
    __shared__ float sscale[TILE_M];

    int tid = threadIdx.x;
    int lane = tid & 63, w = tid >> 6;         // 8 waves
    int lm = lane & 15, quad = lane >> 4;

    // ---- async staging: global -> LDS DMA, pre-swizzled source ----
    constexpr int CPR = KH / 8;                // 16B chunks per row (16 / 8)
    constexpr int IPW = (TILE_M * CPR) / 512;  // DMA insts per wave per stage (8 / 4)
    constexpr int RPI = 64 / CPR;              // rows covered per inst (4 / 8)
    int rl = lane / CPR;
    int cs = lane % CPR;
    auto STAGE = [&](int s, int kh) {
        _Float16* base = sbuf + s * AEL;
        #pragma unroll
        for (int i = 0; i < IPW; i++) {
            int rr  = (w * IPW + i) * RPI + rl;
            int src = esrc[ts + ((rr < nr) ? rr : 0)];
            int c   = cs ^ (rr & 7);           // pre-swizzled source chunk
            const _Float16* gp = hin + (size_t)src * K + kh + c * 8;
            _Float16* lp = base + (w * IPW + i) * 512;   // wave-uniform 1KB
            __builtin_amdgcn_global_load_lds(
                (const __attribute__((address_space(1))) void*)gp,
                (__attribute__((address_space(3))) void*)lp,
                16, 0, 0);
        }
    };

    f32x4 acc[16][2] = {};
    // wave w owns cols [w*32, w*32+32)
    const _Float16* Bbase = Wt + ((size_t)r * HDIM + w * 32 + lm) * K + quad * 8;
    int axor = lm & 7;
    auto MFMA = [&](int s, int kh) {
        const _Float16* base = sbuf + s * AEL;
        for (int kk = 0; kk < KH; kk += 32) {
            int cidx = (((kk >> 3) + quad) ^ axor) * 8;   // swizzled read offset
            half8 b0 = *(const half8*)(Bbase + kh + kk);
            half8 b1 = *(const half8*)(Bbase + 16 * K + kh + kk);
            #pragma unroll
            for (int mt = 0; mt < 16; mt++) {
                half8 a = *(const half8*)(base + (mt * 16 + lm) * KH + cidx);
                acc[mt][0] = __builtin_amdgcn_mfma_f32_16x16x32_f16(a, b0, acc[mt][0], 0, 0, 0);
                acc[mt][1] = __builtin_amdgcn_mfma_f32_16x16x32_f16(a, b1, acc[mt][1], 0, 0, 0);
            }
        }
    };

    STAGE(0, 0);
    if (tid < TILE_M) {
        if (tid < nr) { sq[tid] = eq[ts + tid]; sscale[tid] = escale[ts + tid]; }
        else          { sq[tid] = 0;            sscale[tid] = 0.f; }
    }
    __syncthreads();                 // stage-0 DMA complete
    if constexpr (NST == 2) {
        STAGE(1, KH);                // in flight under stage-0 MFMA
        MFMA(0, 0);
        __syncthreads();             // stage-1 DMA complete (drain overlapped)
        MFMA(1, KH);
    } else {
        MFMA(0, 0);
    }
    __syncthreads();                 // all A reads done before epilogue reuse

    // Epilogue in two 128-row halves through LDS (sbuf reused as [128][264]).
    #pragma unroll
    for (int h = 0; h < 2; h++) {
        #pragma unroll
        for (int ml = 0; ml < 8; ml++) {
            int mt = h * 8 + ml;
            #pragma unroll
            for (int rr = 0; rr < 4; rr++) {
                int lrow = ml * 16 + quad * 4 + rr;
                int row  = h * 128 + lrow;
                float s = sscale[row];
                #pragma unroll
                for (int nt = 0; nt < 2; nt++)
                    sbuf[lrow * SO + w * 32 + nt * 16 + lm] = (_Float16)(acc[mt][nt][rr] * s);
            }
        }
        __syncthreads();
        for (int idx = tid; idx < 128 * 32; idx += 512) {
            int lrow = idx >> 5, seg = idx & 31;
            int row  = h * 128 + lrow;
            if (row < nr) {
                u32x4 v = *(const u32x4*)&sbuf[lrow * SO + seg * 8];
                __builtin_nontemporal_store(v, (u32x4*)(Y + (size_t)sq[row] * HDIM + seg * 8));
            }
        }
        if (h == 0) __syncthreads();   // before half-1 reuses sbuf
    }
}

// ---------------- phase 2: CSR segment-reduce + bias + relu -> h16 ----------------
// Wave-per-node, barrier-free. 2000 blocks x 4 waves. (Unchanged.)
__global__ __launch_bounds__(256)
void reduce_kernel(const _Float16* __restrict__ Y, const int* __restrict__ dst_off,
                   const float* __restrict__ bias, _Float16* __restrict__ hout) {
    int node = blockIdx.x * 4 + (threadIdx.x >> 6);
    int lane = threadIdx.x & 63;
    int start = dst_off[node], end = dst_off[node + 1];
    int c = lane & 31;       // col group: 8 fp16 -> 32 groups = 256 cols
    int r = lane >> 5;       // 2-way row split
    float acc[8] = {0, 0, 0, 0, 0, 0, 0, 0};
    for (int jj = start + r; jj < end; jj += 2) {
        u32x4 u = __builtin_nontemporal_load((const u32x4*)(Y + (size_t)jj * HDIM + c * 8));
        half8 v = *(half8*)&u;
        #pragma unroll
        for (int k = 0; k < 8; k++) acc[k] += (float)v[k];
    }
    #pragma unroll
    for (int k = 0; k < 8; k++) acc[k] += __shfl_down(acc[k], 32, 64);
    if (lane < 32) {
        half8 o;
        #pragma unroll
        for (int k = 0; k < 8; k++) {
            float v = acc[k] + bias[c * 8 + k];
            o[k] = (_Float16)(v > 0.f ? v : 0.f);
        }
        *(half8*)(hout + (size_t)node * HDIM + c * 8) = o;
    }
}

// ---------------- pooling + head ----------------

// R13: gate fused into pool. Block per graph; per node, 256-wide dot for the
// sigmoid gate (wave shfl + 4-slot LDS combine), then acc += g * h[n][t].
// Removes gate kernel + its 4MB global round-trip + the gate buffer.
__global__ void pool_kernel(const _Float16* __restrict__ h, const float* __restrict__ ws_w,
                            const float* __restrict__ ws_b, const int* __restrict__ batch,
                            float* __restrict__ pooled) {
    int g = blockIdx.x, t = threadIdx.x;
    int lane = t & 63, w = t >> 6;
    __shared__ float wsum[4];
    int a = 0, b = NNODES;
    while (a < b) { int m = (a + b) >> 1; if (batch[m] < g) a = m + 1; else b = m; }
    int lo = a;
    b = NNODES;
    while (a < b) { int m = (a + b) >> 1; if (batch[m] < g + 1) a = m + 1; else b = m; }
    int hi = a;
    float wwt = ws_w[t];
    float wb  = ws_b[0];
    float acc = 0.f;
    for (int n = lo; n < hi; n++) {
        float hv = (float)h[(size_t)n * HDIM + t];
        float p = hv * wwt;
        for (int o = 32; o > 0; o >>= 1) p += __shfl_down(p, o, 64);
        if (lane == 0) wsum[w] = p;
        __syncthreads();
        float gt = 1.f / (1.f + __expf(-(wsum[0] + wsum[1] + wsum[2] + wsum[3] + wb)));
        acc += gt * hv;
        __syncthreads();   // before wsum is overwritten next iteration
    }
    pooled[(size_t)g * HDIM + t] = acc;
}

__global__ void head_kernel(const float* __restrict__ pooled,
                            const float* __restrict__ w1, const float* __restrict__ b1,
                            const float* __restrict__ w2, const float* __restrict__ b2,
                            const float* __restrict__ w3, const float* __restrict__ b3,
                            float* __restrict__ out) {
    int b = blockIdx.x, tid = threadIdx.x;   // 64 threads = 1 wave
    __shared__ float sp[HDIM];
    __shared__ float m1[MDIM];
    __shared__ float m2[MDIM];
    for (int i = tid; i < HDIM; i += 64) sp[i] = pooled[(size_t)b * HDIM + i];
    __syncthreads();
    float a = b1[tid];
    for (int i = 0; i < HDIM; i++) a += sp[i] * w1[i * MDIM + tid];
    m1[tid] = a > 0.f ? a : 0.f;
    __syncthreads();
    float c = b2[tid];
    for (int i = 0; i < MDIM; i++) c += m1[i] * w2[i * MDIM + tid];
    m2[tid] = c > 0.f ? c : 0.f;
    __syncthreads();
    float p = m2[tid] * w3[tid];
    for (int o = 32; o > 0; o >>= 1) p += __shfl_down(p, o, 64);
    if (tid == 0) out[b] = p + b3[0];
}

// ---------------- launch ----------------

extern "C" void kernel_launch(void* const* d_in, const int* in_sizes, int n_in,
                              void* d_out, int out_size, void* d_ws, size_t ws_size,
                              hipStream_t stream) {
    const float* x     = (const float*)d_in[0];
    const int*   ei    = (const int*)d_in[1];
    const int*   et    = (const int*)d_in[2];
    const int*   batch = (const int*)d_in[3];
    const float* W1    = (const float*)d_in[4];
    const float* root1 = (const float*)d_in[5];
    const float* b1    = (const float*)d_in[6];
    const float* W2    = (const float*)d_in[7];
    const float* root2 = (const float*)d_in[8];
    const float* b2    = (const float*)d_in[9];
    const float* W3    = (const float*)d_in[10];
    const float* root3 = (const float*)d_in[11];
    const float* b3    = (const float*)d_in[12];
    const float* ws_w  = (const float*)d_in[13];
    const float* ws_b  = (const float*)d_in[14];
    const float* m_w1  = (const float*)d_in[15];
    const float* m_b1  = (const float*)d_in[16];
    const float* m_w2  = (const float*)d_in[17];
    const float* m_b2  = (const float*)d_in[18];
    const float* m_w3  = (const float*)d_in[19];
    const float* m_b3  = (const float*)d_in[20];
    float* out = (float*)d_out;

    char* ws = (char*)d_ws;
    size_t o = 0;
    auto take = [&](size_t bytes) { size_t r = o; o = (o + bytes + 255) & ~(size_t)255; return r; };

    // ---- zeroed region (single memset span) ----
    size_t o_cnt_rn = take((size_t)NREL * NNODES * 4);
    size_t o_tcnt   = take(RP * 4);
    size_t o_tcur   = take(RP * 4);
    size_t o_ddeg   = take((size_t)NNODES * 4);
    size_t o_dcur   = take((size_t)NNODES * 4);
    size_t o_tnrows = take(MAXT * 4);
    size_t o_zero_end = o;
    // ---- rest ----
    size_t o_toff   = take((RP + 1) * 4);
    size_t o_doff   = take((size_t)(NNODES + 1) * 4);
    size_t o_esrc   = take((size_t)EPTOT * 4);
    size_t o_eq     = take((size_t)EPTOT * 4);
    size_t o_escale = take((size_t)EPTOT * 4);
    size_t o_trel   = take(MAXT * 4);
    size_t o_tstart = take(MAXT * 4);
    size_t o_wt1    = take((size_t)RP * HDIM * FDIM * 2);
    size_t o_wt2    = take((size_t)RP * HDIM * HDIM * 2);
    size_t o_wt3    = take((size_t)RP * HDIM * HDIM * 2);
    size_t o_x16    = take((size_t)NNODES * FDIM * 2);
    size_t o_h16    = take((size_t)NNODES * HDIM * 2);
    size_t o_pool   = take((size_t)NGRAPH * HDIM * 4);
    size_t o_y16    = take((size_t)EPTOT * HDIM * 2);   // 102.4 MB

    int*      cnt_rn   = (int*)(ws + o_cnt_rn);
    int*      type_cnt = (int*)(ws + o_tcnt);
    int*      type_cur = (int*)(ws + o_tcur);
    int*      ddeg     = (int*)(ws + o_ddeg);
    int*      dst_cur  = (int*)(ws + o_dcur);
    int*      tnrows   = (int*)(ws + o_tnrows);
    int*      type_off = (int*)(ws + o_toff);
    int*      dst_off  = (int*)(ws + o_doff);
    int*      esrc     = (int*)(ws + o_esrc);
    int*      eq       = (int*)(ws + o_eq);
    float*    escale   = (float*)(ws + o_escale);
    int*      trel     = (int*)(ws + o_trel);
    int*      tstart   = (int*)(ws + o_tstart);
    _Float16* Wt1      = (_Float16*)(ws + o_wt1);
    _Float16* Wt2      = (_Float16*)(ws + o_wt2);
    _Float16* Wt3      = (_Float16*)(ws + o_wt3);
    _Float16* x16      = (_Float16*)(ws + o_x16);
    _Float16* h16      = (_Float16*)(ws + o_h16);
    float*    pooled   = (float*)(ws + o_pool);
    _Float16* Y16      = (_Float16*)(ws + o_y16);

    // Single memset covers cnt_rn..tile_nrows (contiguous by construction).
    hipMemsetAsync(ws + o_cnt_rn, 0, o_zero_end - o_cnt_rn, stream);

    count_kernel<<<(NEDGES + 255) / 256, 256, 0, stream>>>(ei, et, cnt_rn, type_cnt, ddeg);
    scan2_kernel<<<2, 256, 0, stream>>>(type_cnt, type_off, trel, tstart, tnrows, ddeg, dst_off);
    scatter_kernel<<<(EPTOT + 255) / 256, 256, 0, stream>>>(ei, et, cnt_rn, type_off, type_cur,
                                                            dst_off, dst_cur, esrc, eq, escale);
    prep_kernel<<<PREP_TOT, 256, 0, stream>>>(W1, root1, W2, root2, W3, root3, x,
                                              Wt1, Wt2, Wt3, x16);

    // Layer 1 (K=64)
    edge_gemm_kernel<FDIM><<<MAXT, 512, 0, stream>>>(x16, Wt1, esrc, eq, escale,
                                                     trel, tstart, tnrows, Y16);
    reduce_kernel<<<NNODES / 4, 256, 0, stream>>>(Y16, dst_off, b1, h16);

    // Layer 2 (K=256)
    edge_gemm_kernel<HDIM><<<MAXT, 512, 0, stream>>>(h16, Wt2, esrc, eq, escale,
                                                     trel, tstart, tnrows, Y16);
    reduce_kernel<<<NNODES / 4, 256, 0, stream>>>(Y16, dst_off, b2, h16);

    // Layer 3 (K=256)
    edge_gemm_kernel<HDIM><<<MAXT, 512, 0, stream>>>(h16, Wt3, esrc, eq, escale,
                                                     trel, tstart, tnrows, Y16);
    reduce_kernel<<<NNODES / 4, 256, 0, stream>>>(Y16, dst_off, b3, h16);

    pool_kernel<<<NGRAPH, 256, 0, stream>>>(h16, ws_w, ws_b, batch, pooled);
    head_kernel<<<NGRAPH, 64, 0, stream>>>(pooled, m_w1, m_b1, m_w2, m_b2, m_w3, m_b3, out);

    (void)in_sizes; (void)n_in; (void)out_size; (void)ws_size;
}

// Round 14
// 452.830 us; speedup vs baseline: 1.0331x; 1.0331x over previous
//
#include <hip/hip_runtime.h>

// Problem constants (fixed by setup_inputs)
#define NNODES 8000
#define NEDGES 192000
#define NREL   65
#define RP     66      // +1 pseudo-relation for the root/self term
#define HDIM   256
#define FDIM   64
#define NGRAPH 128
#define MDIM   64
#define TILE_M 256
#define MAXT   856     // >= E/256 + 65 + 32 = 847; == 8*107 for XCD swizzle
#define EPTOT  (NEDGES + NNODES)

typedef _Float16 half8 __attribute__((ext_vector_type(8)));
typedef _Float16 half4 __attribute__((ext_vector_type(4)));
typedef float    f32x4 __attribute__((ext_vector_type(4)));
// clang vector type (NOT HIP's struct uint4) — required by __builtin_nontemporal_*
typedef unsigned int u32x4 __attribute__((ext_vector_type(4)));

// ---------------- setup kernels ----------------

__global__ void count_kernel(const int* __restrict__ ei, const int* __restrict__ et,
                             int* __restrict__ cnt_rn, int* __restrict__ type_cnt,
                             int* __restrict__ ddeg) {
    __shared__ int lbin[NREL];
    int tid = threadIdx.x;
    if (tid < NREL) lbin[tid] = 0;
    __syncthreads();
    int e = blockIdx.x * 256 + tid;
    if (e < NEDGES) {
        int t = et[e];
        int d = ei[NEDGES + e];
        atomicAdd(&lbin[t], 1);
        atomicAdd(&cnt_rn[t * NNODES + d], 1);
        atomicAdd(&ddeg[d], 1);
    }
    __syncthreads();
    if (tid < NREL && lbin[tid] > 0) atomicAdd(&type_cnt[tid], lbin[tid]);
}

// scan_tiles (block 0) + dst_scan (block 1) merged (R13; neutral, kept).
__global__ void scan2_kernel(const int* __restrict__ type_cnt, int* __restrict__ type_off,
                             int* __restrict__ tile_rel, int* __restrict__ tile_start,
                             int* __restrict__ tile_nrows,
                             const int* __restrict__ ddeg, int* __restrict__ dst_off) {
    if (blockIdx.x == 0) {
        __shared__ int s_off[RP + 1];
        __shared__ int s_toff[RP + 1];
        if (threadIdx.x == 0) {
            int off = 0, toff = 0;
            for (int r = 0; r < RP; r++) {
                int c = (r < NREL) ? type_cnt[r] : NNODES;
                s_off[r] = off; s_toff[r] = toff;
                off += c; toff += (c + TILE_M - 1) / TILE_M;
            }
            s_off[RP] = off; s_toff[RP] = toff;
            type_off[RP] = off;
        }
        __syncthreads();
        int r = threadIdx.x;
        if (r < RP) {
            type_off[r] = s_off[r];
            int c = s_off[r + 1] - s_off[r];
            int nt = (c + TILE_M - 1) / TILE_M;
            for (int i = 0; i < nt; i++) {
                int idx = s_toff[r] + i;
                tile_rel[idx]   = r;
                tile_start[idx] = s_off[r] + i * TILE_M;
                tile_nrows[idx] = min(TILE_M, c - i * TILE_M);
            }
        }
    } else {
        __shared__ int part[256];
        int t = threadIdx.x;
        int base = t * 32;
        int s = 0;
        for (int i = 0; i < 32; i++) {
            int n = base + i;
            if (n < NNODES) s += ddeg[n] + 1;
        }
        part[t] = s;
        __syncthreads();
        if (t == 0) {
            int run = 0;
            for (int i = 0; i < 256; i++) { int tmp = part[i]; part[i] = run; run += tmp; }
            dst_off[NNODES] = run;   // == EPTOT
        }
        __syncthreads();
        int run = part[t];
        for (int i = 0; i < 32; i++) {
            int n = base + i;
            if (n < NNODES) { dst_off[n] = run; run += ddeg[n] + 1; }
        }
    }
}

// Relation-sorted slot p (block-aggregated rank) + dst-sorted output slot q.
__global__ void scatter_kernel(const int* __restrict__ ei, const int* __restrict__ et,
                               const int* __restrict__ cnt_rn, const int* __restrict__ type_off,
                               int* __restrict__ type_cur,
                               const int* __restrict__ dst_off, int* __restrict__ dst_cur,
                               int* __restrict__ esrc, int* __restrict__ eq,
                               float* __restrict__ escale) {
    __shared__ int lbin[NREL];
    __shared__ int gbase[NREL];
    int tid = threadIdx.x;
    if (tid < NREL) lbin[tid] = 0;
    __syncthreads();
    int i = blockIdx.x * 256 + tid;
    int t = 0, lrank = 0;
    bool is_edge = (i < NEDGES);
    if (is_edge) {
        t = et[i];
        lrank = atomicAdd(&lbin[t], 1);
    }
    __syncthreads();
    if (tid < NREL && lbin[tid] > 0) gbase[tid] = atomicAdd(&type_cur[tid], lbin[tid]);
    __syncthreads();
    if (is_edge) {
        int d = ei[NEDGES + i];
        int p = type_off[t] + gbase[t] + lrank;
        int q = dst_off[d] + atomicAdd(&dst_cur[d], 1);
        esrc[p] = ei[i];
        eq[p] = q;
        escale[p] = 1.0f / (float)cnt_rn[t * NNODES + d];
    } else if (i < EPTOT) {
        int n = i - NEDGES;
        int p = NEDGES + n;      // root pseudo-relation segment starts at E
        int q = dst_off[n] + atomicAdd(&dst_cur[n], 1);
        esrc[p] = n; eq[p] = q; escale[p] = 1.0f;
    }
}

// convW x3 + conv_x merged (R13; neutral, kept).
__device__ __forceinline__ void convW_body(const float* __restrict__ W,
                                           const float* __restrict__ root,
                                           _Float16* __restrict__ Wt, int K, int b) {
    int nk = K / 32;
    int r   = b / (nk * 8);
    int rem = b % (nk * 8);
    int k0  = (rem / 8) * 32, n0 = (rem % 8) * 32;
    const float* src = (r < NREL) ? (W + (size_t)r * K * HDIM) : root;
    __shared__ float tile[32][33];
    int tj = threadIdx.x & 31, ti = threadIdx.x >> 5;
    #pragma unroll
    for (int s = 0; s < 4; s++) {
        int i = ti + s * 8;
        tile[i][tj] = src[(size_t)(k0 + i) * HDIM + n0 + tj];
    }
    __syncthreads();
    #pragma unroll
    for (int s = 0; s < 4; s++) {
        int i = ti + s * 8;
        Wt[((size_t)r * HDIM + (n0 + i)) * K + k0 + tj] = (_Float16)tile[tj][i];
    }
}

#define PREP_B1 (RP * (FDIM / 32) * 8)            // 1056
#define PREP_B2 (RP * (HDIM / 32) * 8)            // 4224
#define PREP_BX ((NNODES * FDIM) / 256)           // 2000
#define PREP_TOT (PREP_B1 + 2 * PREP_B2 + PREP_BX)

__global__ void prep_kernel(const float* __restrict__ W1, const float* __restrict__ root1,
                            const float* __restrict__ W2, const float* __restrict__ root2,
                            const float* __restrict__ W3, const float* __restrict__ root3,
                            const float* __restrict__ x,
                            _Float16* __restrict__ Wt1, _Float16* __restrict__ Wt2,
                            _Float16* __restrict__ Wt3, _Float16* __restrict__ x16) {
    int b = blockIdx.x;
    if (b < PREP_B1) {
        convW_body(W1, root1, Wt1, FDIM, b);
    } else if (b < PREP_B1 + PREP_B2) {
        convW_body(W2, root2, Wt2, HDIM, b - PREP_B1);
    } else if (b < PREP_B1 + 2 * PREP_B2) {
        convW_body(W3, root3, Wt3, HDIM, b - PREP_B1 - PREP_B2);
    } else {
        int i = (b - PREP_B1 - 2 * PREP_B2) * 256 + threadIdx.x;
        if (i < NNODES * FDIM) x16[i] = (_Float16)x[i];
    }
}

// ---------------- phase 1: Y16[q] = scale * (h[src] @ W_r) ----------------
// R12 kernel, UNCHANGED (66.5us K=256; tile-geometry axis saturated).
template <int K>
__global__ __launch_bounds__(512)
void edge_gemm_kernel(const _Float16* __restrict__ hin, const _Float16* __restrict__ Wt,
                      const int* __restrict__ esrc, const int* __restrict__ eq,
                      const float* __restrict__ escale,
                      const int* __restrict__ tile_rel, const int* __restrict__ tile_start,
                      const int* __restrict__ tile_nrows,
                      _Float16* __restrict__ Y) {
    // XCD swizzle: relation-sorted tiles colocate per XCD. Bijective: 8*107.
    int bid  = blockIdx.x;
    int tile = (bid & 7) * (MAXT / 8) + (bid >> 3);

    int nr = tile_nrows[tile];
    if (nr == 0) return;
    int r  = tile_rel[tile];
    int ts = tile_start[tile];

    constexpr int KH  = (K > 128) ? 128 : K;   // staged K per pass (128 / 64)
    constexpr int NST = K / KH;                // stages (2 / 1)
    constexpr int SO  = HDIM + 8;              // epilogue out stride = 264
    constexpr int AEL = TILE_M * KH;           // per-stage A tile (linear, unpadded)
    constexpr int OEL = 128 * SO;              // 128-row epilogue half = 33792
    constexpr int EL  = (NST * AEL > OEL) ? NST * AEL : OEL;
    __shared__ _Float16 sbuf[EL];              // A stage buffers, then epilogue
    __shared__ int   sq[TILE_M];
    __shared__ float sscale[TILE_M];

    int tid = threadIdx.x;
    int lane = tid & 63, w = tid >> 6;         // 8 waves
    int lm = lane & 15, quad = lane >> 4;

    // ---- async staging: global -> LDS DMA, pre-swizzled source ----
    constexpr int CPR = KH / 8;                // 16B chunks per row (16 / 8)
    constexpr int IPW = (TILE_M * CPR) / 512;  // DMA insts per wave per stage (8 / 4)
    constexpr int RPI = 64 / CPR;              // rows covered per inst (4 / 8)
    int rl = lane / CPR;
    int cs = lane % CPR;
    auto STAGE = [&](int s, int kh) {
        _Float16* base = sbuf + s * AEL;
        #pragma unroll
        for (int i = 0; i < IPW; i++) {
            int rr  = (w * IPW + i) * RPI + rl;
            int src = esrc[ts + ((rr < nr) ? rr : 0)];
            int c   = cs ^ (rr & 7);           // pre-swizzled source chunk
            const _Float16* gp = hin + (size_t)src * K + kh + c * 8;
            _Float16* lp = base + (w * IPW + i) * 512;   // wave-uniform 1KB
            __builtin_amdgcn_global_load_lds(
                (const __attribute__((address_space(1))) void*)gp,
                (__attribute__((address_space(3))) void*)lp,
                16, 0, 0);
        }
    };

    f32x4 acc[16][2] = {};
    // wave w owns cols [w*32, w*32+32)
    const _Float16* Bbase = Wt + ((size_t)r * HDIM + w * 32 + lm) * K + quad * 8;
    int axor = lm & 7;
    auto MFMA = [&](int s, int kh) {
        const _Float16* base = sbuf + s * AEL;
        for (int kk = 0; kk < KH; kk += 32) {
            int cidx = (((kk >> 3) + quad) ^ axor) * 8;   // swizzled read offset
            half8 b0 = *(const half8*)(Bbase + kh + kk);
            half8 b1 = *(const half8*)(Bbase + 16 * K + kh + kk);
            #pragma unroll
            for (int mt = 0; mt < 16; mt++) {
                half8 a = *(const half8*)(base + (mt * 16 + lm) * KH + cidx);
                acc[mt][0] = __builtin_amdgcn_mfma_f32_16x16x32_f16(a, b0, acc[mt][0], 0, 0, 0);
                acc[mt][1] = __builtin_amdgcn_mfma_f32_16x16x32_f16(a, b1, acc[mt][1], 0, 0, 0);
            }
        }
    };

    STAGE(0, 0);
    if (tid < TILE_M) {
        if (tid < nr) { sq[tid] = eq[ts + tid]; sscale[tid] = escale[ts + tid]; }
        else          { sq[tid] = 0;            sscale[tid] = 0.f; }
    }
    __syncthreads();                 // stage-0 DMA complete
    if constexpr (NST == 2) {
        STAGE(1, KH);                // in flight under stage-0 MFMA
        MFMA(0, 0);
        __syncthreads();             // stage-1 DMA complete (drain overlapped)
        MFMA(1, KH);
    } else {
        MFMA(0, 0);
    }
    __syncthreads();                 // all A reads done before epilogue reuse

    // Epilogue in two 128-row halves through LDS (sbuf reused as [128][264]).
    #pragma unroll
    for (int h = 0; h < 2; h++) {
        #pragma unroll
        for (int ml = 0; ml < 8; ml++) {
            int mt = h * 8 + ml;
            #pragma unroll
            for (int rr = 0; rr < 4; rr++) {
                int lrow = ml * 16 + quad * 4 + rr;
                int row  = h * 128 + lrow;
                float s = sscale[row];
                #pragma unroll
                for (int nt = 0; nt < 2; nt++)
                    sbuf[lrow * SO + w * 32 + nt * 16 + lm] = (_Float16)(acc[mt][nt][rr] * s);
            }
        }
        __syncthreads();
        for (int idx = tid; idx < 128 * 32; idx += 512) {
            int lrow = idx >> 5, seg = idx & 31;
            int row  = h * 128 + lrow;
            if (row < nr) {
                u32x4 v = *(const u32x4*)&sbuf[lrow * SO + seg * 8];
                __builtin_nontemporal_store(v, (u32x4*)(Y + (size_t)sq[row] * HDIM + seg * 8));
            }
        }
        if (h == 0) __syncthreads();   // before half-1 reuses sbuf
    }
}

// ---------------- phase 2: CSR segment-reduce + bias + relu -> h16 ----------------
// R14: PLAIN loads (NT dropped — m13's 6.3 TB/s ceiling was measured with
// regular vector loads; NT reads may throttle the stream) + unroll 4 to
// deepen the in-flight load window. Wave-per-node, barrier-free.
__global__ __launch_bounds__(256)
void reduce_kernel(const _Float16* __restrict__ Y, const int* __restrict__ dst_off,
                   const float* __restrict__ bias, _Float16* __restrict__ hout) {
    int node = blockIdx.x * 4 + (threadIdx.x >> 6);
    int lane = threadIdx.x & 63;
    int start = dst_off[node], end = dst_off[node + 1];
    int c = lane & 31;       // col group: 8 fp16 -> 32 groups = 256 cols
    int r = lane >> 5;       // 2-way row split
    float acc[8] = {0, 0, 0, 0, 0, 0, 0, 0};
    #pragma unroll 4
    for (int jj = start + r; jj < end; jj += 2) {
        half8 v = *(const half8*)(Y + (size_t)jj * HDIM + c * 8);
        #pragma unroll
        for (int k = 0; k < 8; k++) acc[k] += (float)v[k];
    }
    #pragma unroll
    for (int k = 0; k < 8; k++) acc[k] += __shfl_down(acc[k], 32, 64);
    if (lane < 32) {
        half8 o;
        #pragma unroll
        for (int k = 0; k < 8; k++) {
            float v = acc[k] + bias[c * 8 + k];
            o[k] = (_Float16)(v > 0.f ? v : 0.f);
        }
        *(half8*)(hout + (size_t)node * HDIM + c * 8) = o;
    }
}

// ---------------- pooling + head (R12 versions — R13 fusion regressed) ----------------

// One wave per node: gate[n] = sigmoid(h[n] . ws_w + ws_b)
__global__ void gate_kernel(const _Float16* __restrict__ h, const float* __restrict__ ws_w,
                            const float* __restrict__ ws_b, float* __restrict__ gate) {
    int node = blockIdx.x * 4 + (threadIdx.x >> 6);
    int lane = threadIdx.x & 63;
    half4 v = *(const half4*)(h + (size_t)node * HDIM + lane * 4);
    float s = 0.f;
    #pragma unroll
    for (int k = 0; k < 4; k++) s += (float)v[k] * ws_w[lane * 4 + k];
    for (int o = 32; o > 0; o >>= 1) s += __shfl_down(s, o, 64);
    if (lane == 0) gate[node] = 1.f / (1.f + __expf(-(s + ws_b[0])));
}

// One block per graph; batch is sorted, so segments are contiguous (binary search).
__global__ void pool_kernel(const _Float16* __restrict__ h, const float* __restrict__ gate,
                            const int* __restrict__ batch, float* __restrict__ pooled) {
    int g = blockIdx.x, t = threadIdx.x;
    int a = 0, b = NNODES;
    while (a < b) { int m = (a + b) >> 1; if (batch[m] < g) a = m + 1; else b = m; }
    int lo = a;
    b = NNODES;
    while (a < b) { int m = (a + b) >> 1; if (batch[m] < g + 1) a = m + 1; else b = m; }
    int hi = a;
    float acc = 0.f;
    for (int n = lo; n < hi; n++)
        acc += gate[n] * (float)h[(size_t)n * HDIM + t];
    pooled[(size_t)g * HDIM + t] = acc;
}

__global__ void head_kernel(const float* __restrict__ pooled,
                            const float* __restrict__ w1, const float* __restrict__ b1,
                            const float* __restrict__ w2, const float* __restrict__ b2,
                            const float* __restrict__ w3, const float* __restrict__ b3,
                            float* __restrict__ out) {
    int b = blockIdx.x, tid = threadIdx.x;   // 64 threads = 1 wave
    __shared__ float sp[HDIM];
    __shared__ float m1[MDIM];
    __shared__ float m2[MDIM];
    for (int i = tid; i < HDIM; i += 64) sp[i] = pooled[(size_t)b * HDIM + i];
    __syncthreads();
    float a = b1[tid];
    for (int i = 0; i < HDIM; i++) a += sp[i] * w1[i * MDIM + tid];
    m1[tid] = a > 0.f ? a : 0.f;
    __syncthreads();
    float c = b2[tid];
    for (int i = 0; i < MDIM; i++) c += m1[i] * w2[i * MDIM + tid];
    m2[tid] = c > 0.f ? c : 0.f;
    __syncthreads();
    float p = m2[tid] * w3[tid];
    for (int o = 32; o > 0; o >>= 1) p += __shfl_down(p, o, 64);
    if (tid == 0) out[b] = p + b3[0];
}

// ---------------- launch ----------------

extern "C" void kernel_launch(void* const* d_in, const int* in_sizes, int n_in,
                              void* d_out, int out_size, void* d_ws, size_t ws_size,
                              hipStream_t stream) {
    const float* x     = (const float*)d_in[0];
    const int*   ei    = (const int*)d_in[1];
    const int*   et    = (const int*)d_in[2];
    const int*   batch = (const int*)d_in[3];
    const float* W1    = (const float*)d_in[4];
    const float* root1 = (const float*)d_in[5];
    const float* b1    = (const float*)d_in[6];
    const float* W2    = (const float*)d_in[7];
    const float* root2 = (const float*)d_in[8];
    const float* b2    = (const float*)d_in[9];
    const float* W3    = (const float*)d_in[10];
    const float* root3 = (const float*)d_in[11];
    const float* b3    = (const float*)d_in[12];
    const float* ws_w  = (const float*)d_in[13];
    const float* ws_b  = (const float*)d_in[14];
    const float* m_w1  = (const float*)d_in[15];
    const float* m_b1  = (const float*)d_in[16];
    const float* m_w2  = (const float*)d_in[17];
    const float* m_b2  = (const float*)d_in[18];
    const float* m_w3  = (const float*)d_in[19];
    const float* m_b3  = (const float*)d_in[20];
    float* out = (float*)d_out;

    char* ws = (char*)d_ws;
    size_t o = 0;
    auto take = [&](size_t bytes) { size_t r = o; o = (o + bytes + 255) & ~(size_t)255; return r; };

    // ---- zeroed region (single memset span) ----
    size_t o_cnt_rn = take((size_t)NREL * NNODES * 4);
    size_t o_tcnt   = take(RP * 4);
    size_t o_tcur   = take(RP * 4);
    size_t o_ddeg   = take((size_t)NNODES * 4);
    size_t o_dcur   = take((size_t)NNODES * 4);
    size_t o_tnrows = take(MAXT * 4);
    size_t o_zero_end = o;
    // ---- rest ----
    size_t o_toff   = take((RP + 1) * 4);
    size_t o_doff   = take((size_t)(NNODES + 1) * 4);
    size_t o_esrc   = take((size_t)EPTOT * 4);
    size_t o_eq     = take((size_t)EPTOT * 4);
    size_t o_escale = take((size_t)EPTOT * 4);
    size_t o_trel   = take(MAXT * 4);
    size_t o_tstart = take(MAXT * 4);
    size_t o_wt1    = take((size_t)RP * HDIM * FDIM * 2);
    size_t o_wt2    = take((size_t)RP * HDIM * HDIM * 2);
    size_t o_wt3    = take((size_t)RP * HDIM * HDIM * 2);
    size_t o_x16    = take((size_t)NNODES * FDIM * 2);
    size_t o_h16    = take((size_t)NNODES * HDIM * 2);
    size_t o_gate   = take((size_t)NNODES * 4);
    size_t o_pool   = take((size_t)NGRAPH * HDIM * 4);
    size_t o_y16    = take((size_t)EPTOT * HDIM * 2);   // 102.4 MB

    int*      cnt_rn   = (int*)(ws + o_cnt_rn);
    int*      type_cnt = (int*)(ws + o_tcnt);
    int*      type_cur = (int*)(ws + o_tcur);
    int*      ddeg     = (int*)(ws + o_ddeg);
    int*      dst_cur  = (int*)(ws + o_dcur);
    int*      tnrows   = (int*)(ws + o_tnrows);
    int*      type_off = (int*)(ws + o_toff);
    int*      dst_off  = (int*)(ws + o_doff);
    int*      esrc     = (int*)(ws + o_esrc);
    int*      eq       = (int*)(ws + o_eq);
    float*    escale   = (float*)(ws + o_escale);
    int*      trel     = (int*)(ws + o_trel);
    int*      tstart   = (int*)(ws + o_tstart);
    _Float16* Wt1      = (_Float16*)(ws + o_wt1);
    _Float16* Wt2      = (_Float16*)(ws + o_wt2);
    _Float16* Wt3      = (_Float16*)(ws + o_wt3);
    _Float16* x16      = (_Float16*)(ws + o_x16);
    _Float16* h16      = (_Float16*)(ws + o_h16);
    float*    gate     = (float*)(ws + o_gate);
    float*    pooled   = (float*)(ws + o_pool);
    _Float16* Y16      = (_Float16*)(ws + o_y16);

    // Single memset covers cnt_rn..tile_nrows (contiguous by construction).
    hipMemsetAsync(ws + o_cnt_rn, 0, o_zero_end - o_cnt_rn, stream);

    count_kernel<<<(NEDGES + 255) / 256, 256, 0, stream>>>(ei, et, cnt_rn, type_cnt, ddeg);
    scan2_kernel<<<2, 256, 0, stream>>>(type_cnt, type_off, trel, tstart, tnrows, ddeg, dst_off);
    scatter_kernel<<<(EPTOT + 255) / 256, 256, 0, stream>>>(ei, et, cnt_rn, type_off, type_cur,
                                                            dst_off, dst_cur, esrc, eq, escale);
    prep_kernel<<<PREP_TOT, 256, 0, stream>>>(W1, root1, W2, root2, W3, root3, x,
                                              Wt1, Wt2, Wt3, x16);

    // Layer 1 (K=64)
    edge_gemm_kernel<FDIM><<<MAXT, 512, 0, stream>>>(x16, Wt1, esrc, eq, escale,
                                                     trel, tstart, tnrows, Y16);
    reduce_kernel<<<NNODES / 4, 256, 0, stream>>>(Y16, dst_off, b1, h16);

    // Layer 2 (K=256)
    edge_gemm_kernel<HDIM><<<MAXT, 512, 0, stream>>>(h16, Wt2, esrc, eq, escale,
                                                     trel, tstart, tnrows, Y16);
    reduce_kernel<<<NNODES / 4, 256, 0, stream>>>(Y16, dst_off, b2, h16);

    // Layer 3 (K=256)
    edge_gemm_kernel<HDIM><<<MAXT, 512, 0, stream>>>(h16, Wt3, esrc, eq, escale,
                                                     trel, tstart, tnrows, Y16);
    reduce_kernel<<<NNODES / 4, 256, 0, stream>>>(Y16, dst_off, b3, h16);

    gate_kernel<<<NNODES / 4, 256, 0, stream>>>(h16, ws_w, ws_b, gate);
    pool_kernel<<<NGRAPH, 256, 0, stream>>>(h16, gate, batch, pooled);
    head_kernel<<<NGRAPH, 64, 0, stream>>>(pooled, m_w1, m_b1, m_w2, m_b2, m_w3, m_b3, out);

    (void)in_sizes; (void)n_in; (void)out_size; (void)ws_size;
}

// Round 15
// 441.445 us; speedup vs baseline: 1.0598x; 1.0258x over previous
//
#include <hip/hip_runtime.h>

// Problem constants (fixed by setup_inputs)
#define NNODES 8000
#define NEDGES 192000
#define NREL   65
#define RP     66      // +1 pseudo-relation for the root/self term
#define HDIM   256
#define FDIM   64
#define NGRAPH 128
#define MDIM   64
#define TILE_M 256
#define MAXT   856     // >= E/256 + 65 + 32 = 847; == 8*107 for XCD swizzle
#define EPTOT  (NEDGES + NNODES)

typedef _Float16 half8 __attribute__((ext_vector_type(8)));
typedef _Float16 half4 __attribute__((ext_vector_type(4)));
typedef float    f32x4 __attribute__((ext_vector_type(4)));
// clang vector type (NOT HIP's struct uint4) — required by __builtin_nontemporal_*
typedef unsigned int u32x4 __attribute__((ext_vector_type(4)));

// ---------------- setup kernels ----------------

__global__ void count_kernel(const int* __restrict__ ei, const int* __restrict__ et,
                             int* __restrict__ cnt_rn, int* __restrict__ type_cnt,
                             int* __restrict__ ddeg) {
    __shared__ int lbin[NREL];
    int tid = threadIdx.x;
    if (tid < NREL) lbin[tid] = 0;
    __syncthreads();
    int e = blockIdx.x * 256 + tid;
    if (e < NEDGES) {
        int t = et[e];
        int d = ei[NEDGES + e];
        atomicAdd(&lbin[t], 1);
        atomicAdd(&cnt_rn[t * NNODES + d], 1);
        atomicAdd(&ddeg[d], 1);
    }
    __syncthreads();
    if (tid < NREL && lbin[tid] > 0) atomicAdd(&type_cnt[tid], lbin[tid]);
}

// scan_tiles (block 0) + dst_scan (block 1) merged (R13; neutral, kept).
__global__ void scan2_kernel(const int* __restrict__ type_cnt, int* __restrict__ type_off,
                             int* __restrict__ tile_rel, int* __restrict__ tile_start,
                             int* __restrict__ tile_nrows,
                             const int* __restrict__ ddeg, int* __restrict__ dst_off) {
    if (blockIdx.x == 0) {
        __shared__ int s_off[RP + 1];
        __shared__ int s_toff[RP + 1];
        if (threadIdx.x == 0) {
            int off = 0, toff = 0;
            for (int r = 0; r < RP; r++) {
                int c = (r < NREL) ? type_cnt[r] : NNODES;
                s_off[r] = off; s_toff[r] = toff;
                off += c; toff += (c + TILE_M - 1) / TILE_M;
            }
            s_off[RP] = off; s_toff[RP] = toff;
            type_off[RP] = off;
        }
        __syncthreads();
        int r = threadIdx.x;
        if (r < RP) {
            type_off[r] = s_off[r];
            int c = s_off[r + 1] - s_off[r];
            int nt = (c + TILE_M - 1) / TILE_M;
            for (int i = 0; i < nt; i++) {
                int idx = s_toff[r] + i;
                tile_rel[idx]   = r;
                tile_start[idx] = s_off[r] + i * TILE_M;
                tile_nrows[idx] = min(TILE_M, c - i * TILE_M);
            }
        }
    } else {
        __shared__ int part[256];
        int t = threadIdx.x;
        int base = t * 32;
        int s = 0;
        for (int i = 0; i < 32; i++) {
            int n = base + i;
            if (n < NNODES) s += ddeg[n] + 1;
        }
        part[t] = s;
        __syncthreads();
        if (t == 0) {
            int run = 0;
            for (int i = 0; i < 256; i++) { int tmp = part[i]; part[i] = run; run += tmp; }
            dst_off[NNODES] = run;   // == EPTOT
        }
        __syncthreads();
        int run = part[t];
        for (int i = 0; i < 32; i++) {
            int n = base + i;
            if (n < NNODES) { dst_off[n] = run; run += ddeg[n] + 1; }
        }
    }
}

// R15: emits the INVERSE permutation qp[q] = p (dst-slot -> relation-slot).
// Y is now stored in p-order (sequential per tile); reduce gathers via qp.
__global__ void scatter_kernel(const int* __restrict__ ei, const int* __restrict__ et,
                               const int* __restrict__ cnt_rn, const int* __restrict__ type_off,
                               int* __restrict__ type_cur,
                               const int* __restrict__ dst_off, int* __restrict__ dst_cur,
                               int* __restrict__ esrc, int* __restrict__ qp,
                               float* __restrict__ escale) {
    __shared__ int lbin[NREL];
    __shared__ int gbase[NREL];
    int tid = threadIdx.x;
    if (tid < NREL) lbin[tid] = 0;
    __syncthreads();
    int i = blockIdx.x * 256 + tid;
    int t = 0, lrank = 0;
    bool is_edge = (i < NEDGES);
    if (is_edge) {
        t = et[i];
        lrank = atomicAdd(&lbin[t], 1);
    }
    __syncthreads();
    if (tid < NREL && lbin[tid] > 0) gbase[tid] = atomicAdd(&type_cur[tid], lbin[tid]);
    __syncthreads();
    if (is_edge) {
        int d = ei[NEDGES + i];
        int p = type_off[t] + gbase[t] + lrank;
        int q = dst_off[d] + atomicAdd(&dst_cur[d], 1);
        esrc[p] = ei[i];
        qp[q] = p;
        escale[p] = 1.0f / (float)cnt_rn[t * NNODES + d];
    } else if (i < EPTOT) {
        int n = i - NEDGES;
        int p = NEDGES + n;      // root pseudo-relation segment starts at E
        int q = dst_off[n] + atomicAdd(&dst_cur[n], 1);
        esrc[p] = n; qp[q] = p; escale[p] = 1.0f;
    }
}

// convW x3 + conv_x merged (R13; neutral, kept).
__device__ __forceinline__ void convW_body(const float* __restrict__ W,
                                           const float* __restrict__ root,
                                           _Float16* __restrict__ Wt, int K, int b) {
    int nk = K / 32;
    int r   = b / (nk * 8);
    int rem = b % (nk * 8);
    int k0  = (rem / 8) * 32, n0 = (rem % 8) * 32;
    const float* src = (r < NREL) ? (W + (size_t)r * K * HDIM) : root;
    __shared__ float tile[32][33];
    int tj = threadIdx.x & 31, ti = threadIdx.x >> 5;
    #pragma unroll
    for (int s = 0; s < 4; s++) {
        int i = ti + s * 8;
        tile[i][tj] = src[(size_t)(k0 + i) * HDIM + n0 + tj];
    }
    __syncthreads();
    #pragma unroll
    for (int s = 0; s < 4; s++) {
        int i = ti + s * 8;
        Wt[((size_t)r * HDIM + (n0 + i)) * K + k0 + tj] = (_Float16)tile[tj][i];
    }
}

#define PREP_B1 (RP * (FDIM / 32) * 8)            // 1056
#define PREP_B2 (RP * (HDIM / 32) * 8)            // 4224
#define PREP_BX ((NNODES * FDIM) / 256)           // 2000
#define PREP_TOT (PREP_B1 + 2 * PREP_B2 + PREP_BX)

__global__ void prep_kernel(const float* __restrict__ W1, const float* __restrict__ root1,
                            const float* __restrict__ W2, const float* __restrict__ root2,
                            const float* __restrict__ W3, const float* __restrict__ root3,
                            const float* __restrict__ x,
                            _Float16* __restrict__ Wt1, _Float16* __restrict__ Wt2,
                            _Float16* __restrict__ Wt3, _Float16* __restrict__ x16) {
    int b = blockIdx.x;
    if (b < PREP_B1) {
        convW_body(W1, root1, Wt1, FDIM, b);
    } else if (b < PREP_B1 + PREP_B2) {
        convW_body(W2, root2, Wt2, HDIM, b - PREP_B1);
    } else if (b < PREP_B1 + 2 * PREP_B2) {
        convW_body(W3, root3, Wt3, HDIM, b - PREP_B1 - PREP_B2);
    } else {
        int i = (b - PREP_B1 - 2 * PREP_B2) * 256 + threadIdx.x;
        if (i < NNODES * FDIM) x16[i] = (_Float16)x[i];
    }
}

// ---------------- phase 1: Y16[p] = scale * (h[src] @ W_r), p-order stores ----------------
// R15: Y stored SEQUENTIALLY (row ts+row). Each tile's 128KB of NT stores is
// one contiguous stream (was random 512B segments to sq[row] — the suspected
// ~2TB/s write throttle). The dst-permutation moves to reduce (gather by qp).
template <int K>
__global__ __launch_bounds__(512)
void edge_gemm_kernel(const _Float16* __restrict__ hin, const _Float16* __restrict__ Wt,
                      const int* __restrict__ esrc,
                      const float* __restrict__ escale,
                      const int* __restrict__ tile_rel, const int* __restrict__ tile_start,
                      const int* __restrict__ tile_nrows,
                      _Float16* __restrict__ Y) {
    // XCD swizzle: relation-sorted tiles colocate per XCD. Bijective: 8*107.
    int bid  = blockIdx.x;
    int tile = (bid & 7) * (MAXT / 8) + (bid >> 3);

    int nr = tile_nrows[tile];
    if (nr == 0) return;
    int r  = tile_rel[tile];
    int ts = tile_start[tile];

    constexpr int KH  = (K > 128) ? 128 : K;   // staged K per pass (128 / 64)
    constexpr int NST = K / KH;                // stages (2 / 1)
    constexpr int SO  = HDIM + 8;              // epilogue out stride = 264
    constexpr int AEL = TILE_M * KH;           // per-stage A tile (linear, unpadded)
    constexpr int OEL = 128 * SO;              // 128-row epilogue half = 33792
    constexpr int EL  = (NST * AEL > OEL) ? NST * AEL : OEL;
    __shared__ _Float16 sbuf[EL];              // A stage buffers, then epilogue
    __shared__ float sscale[TILE_M];

    int tid = threadIdx.x;
    int lane = tid & 63, w = tid >> 6;         // 8 waves
    int lm = lane & 15, quad = lane >> 4;

    // ---- async staging: global -> LDS DMA, pre-swizzled source ----
    constexpr int CPR = KH / 8;                // 16B chunks per row (16 / 8)
    constexpr int IPW = (TILE_M * CPR) / 512;  // DMA insts per wave per stage (8 / 4)
    constexpr int RPI = 64 / CPR;              // rows covered per inst (4 / 8)
    int rl = lane / CPR;
    int cs = lane % CPR;
    auto STAGE = [&](int s, int kh) {
        _Float16* base = sbuf + s * AEL;
        #pragma unroll
        for (int i = 0; i < IPW; i++) {
            int rr  = (w * IPW + i) * RPI + rl;
            int src = esrc[ts + ((rr < nr) ? rr : 0)];
            int c   = cs ^ (rr & 7);           // pre-swizzled source chunk
            const _Float16* gp = hin + (size_t)src * K + kh + c * 8;
            _Float16* lp = base + (w * IPW + i) * 512;   // wave-uniform 1KB
            __builtin_amdgcn_global_load_lds(
                (const __attribute__((address_space(1))) void*)gp,
                (__attribute__((address_space(3))) void*)lp,
                16, 0, 0);
        }
    };

    f32x4 acc[16][2] = {};
    // wave w owns cols [w*32, w*32+32)
    const _Float16* Bbase = Wt + ((size_t)r * HDIM + w * 32 + lm) * K + quad * 8;
    int axor = lm & 7;
    auto MFMA = [&](int s, int kh) {
        const _Float16* base = sbuf + s * AEL;
        for (int kk = 0; kk < KH; kk += 32) {
            int cidx = (((kk >> 3) + quad) ^ axor) * 8;   // swizzled read offset
            half8 b0 = *(const half8*)(Bbase + kh + kk);
            half8 b1 = *(const half8*)(Bbase + 16 * K + kh + kk);
            #pragma unroll
            for (int mt = 0; mt < 16; mt++) {
                half8 a = *(const half8*)(base + (mt * 16 + lm) * KH + cidx);
                acc[mt][0] = __builtin_amdgcn_mfma_f32_16x16x32_f16(a, b0, acc[mt][0], 0, 0, 0);
                acc[mt][1] = __builtin_amdgcn_mfma_f32_16x16x32_f16(a, b1, acc[mt][1], 0, 0, 0);
            }
        }
    };

    STAGE(0, 0);
    if (tid < TILE_M) sscale[tid] = (tid < nr) ? escale[ts + tid] : 0.f;
    __syncthreads();                 // stage-0 DMA complete
    if constexpr (NST == 2) {
        STAGE(1, KH);                // in flight under stage-0 MFMA
        MFMA(0, 0);
        __syncthreads();             // stage-1 DMA complete (drain overlapped)
        MFMA(1, KH);
    } else {
        MFMA(0, 0);
    }
    __syncthreads();                 // all A reads done before epilogue reuse

    // Epilogue in two 128-row halves through LDS (sbuf reused as [128][264]).
    #pragma unroll
    for (int h = 0; h < 2; h++) {
        #pragma unroll
        for (int ml = 0; ml < 8; ml++) {
            int mt = h * 8 + ml;
            #pragma unroll
            for (int rr = 0; rr < 4; rr++) {
                int lrow = ml * 16 + quad * 4 + rr;
                int row  = h * 128 + lrow;
                float s = sscale[row];
                #pragma unroll
                for (int nt = 0; nt < 2; nt++)
                    sbuf[lrow * SO + w * 32 + nt * 16 + lm] = (_Float16)(acc[mt][nt][rr] * s);
            }
        }
        __syncthreads();
        // 128 rows x 512B, SEQUENTIAL NT stream: consecutive tids cover
        // consecutive 16B chunks of consecutive rows (64KB per sweep).
        for (int idx = tid; idx < 128 * 32; idx += 512) {
            int lrow = idx >> 5, seg = idx & 31;
            int row  = h * 128 + lrow;
            if (row < nr) {
                u32x4 v = *(const u32x4*)&sbuf[lrow * SO + seg * 8];
                __builtin_nontemporal_store(v, (u32x4*)(Y + (size_t)(ts + row) * HDIM + seg * 8));
            }
        }
        if (h == 0) __syncthreads();   // before half-1 reuses sbuf
    }
}

// ---------------- phase 2: CSR segment-reduce + bias + relu -> h16 ----------------
// R15: reduce does the dst-permutation: row p = qp[j], gathered 512B rows.
// NT loads (read-once; keeps 100MB stream out of L2 — fixes R14's gemm
// regression) + unroll 4 for deep in-flight chains. Wave-per-node.
__global__ __launch_bounds__(256)
void reduce_kernel(const _Float16* __restrict__ Y, const int* __restrict__ dst_off,
                   const int* __restrict__ qp,
                   const float* __restrict__ bias, _Float16* __restrict__ hout) {
    int node = blockIdx.x * 4 + (threadIdx.x >> 6);
    int lane = threadIdx.x & 63;
    int start = dst_off[node], end = dst_off[node + 1];
    int c = lane & 31;       // col group: 8 fp16 -> 32 groups = 256 cols
    int r = lane >> 5;       // 2-way row split
    float acc[8] = {0, 0, 0, 0, 0, 0, 0, 0};
    #pragma unroll 4
    for (int jj = start + r; jj < end; jj += 2) {
        int p = qp[jj];
        u32x4 u = __builtin_nontemporal_load((const u32x4*)(Y + (size_t)p * HDIM + c * 8));
        half8 v = *(half8*)&u;
        #pragma unroll
        for (int k = 0; k < 8; k++) acc[k] += (float)v[k];
    }
    #pragma unroll
    for (int k = 0; k < 8; k++) acc[k] += __shfl_down(acc[k], 32, 64);
    if (lane < 32) {
        half8 o;
        #pragma unroll
        for (int k = 0; k < 8; k++) {
            float v = acc[k] + bias[c * 8 + k];
            o[k] = (_Float16)(v > 0.f ? v : 0.f);
        }
        *(half8*)(hout + (size_t)node * HDIM + c * 8) = o;
    }
}

// ---------------- pooling + head ----------------

// One wave per node: gate[n] = sigmoid(h[n] . ws_w + ws_b)
__global__ void gate_kernel(const _Float16* __restrict__ h, const float* __restrict__ ws_w,
                            const float* __restrict__ ws_b, float* __restrict__ gate) {
    int node = blockIdx.x * 4 + (threadIdx.x >> 6);
    int lane = threadIdx.x & 63;
    half4 v = *(const half4*)(h + (size_t)node * HDIM + lane * 4);
    float s = 0.f;
    #pragma unroll
    for (int k = 0; k < 4; k++) s += (float)v[k] * ws_w[lane * 4 + k];
    for (int o = 32; o > 0; o >>= 1) s += __shfl_down(s, o, 64);
    if (lane == 0) gate[node] = 1.f / (1.f + __expf(-(s + ws_b[0])));
}

// One block per graph; batch is sorted, so segments are contiguous (binary search).
__global__ void pool_kernel(const _Float16* __restrict__ h, const float* __restrict__ gate,
                            const int* __restrict__ batch, float* __restrict__ pooled) {
    int g = blockIdx.x, t = threadIdx.x;
    int a = 0, b = NNODES;
    while (a < b) { int m = (a + b) >> 1; if (batch[m] < g) a = m + 1; else b = m; }
    int lo = a;
    b = NNODES;
    while (a < b) { int m = (a + b) >> 1; if (batch[m] < g + 1) a = m + 1; else b = m; }
    int hi = a;
    float acc = 0.f;
    for (int n = lo; n < hi; n++)
        acc += gate[n] * (float)h[(size_t)n * HDIM + t];
    pooled[(size_t)g * HDIM + t] = acc;
}

__global__ void head_kernel(const float* __restrict__ pooled,
                            const float* __restrict__ w1, const float* __restrict__ b1,
                            const float* __restrict__ w2, const float* __restrict__ b2,
                            const float* __restrict__ w3, const float* __restrict__ b3,
                            float* __restrict__ out) {
    int b = blockIdx.x, tid = threadIdx.x;   // 64 threads = 1 wave
    __shared__ float sp[HDIM];
    __shared__ float m1[MDIM];
    __shared__ float m2[MDIM];
    for (int i = tid; i < HDIM; i += 64) sp[i] = pooled[(size_t)b * HDIM + i];
    __syncthreads();
    float a = b1[tid];
    for (int i = 0; i < HDIM; i++) a += sp[i] * w1[i * MDIM + tid];
    m1[tid] = a > 0.f ? a : 0.f;
    __syncthreads();
    float c = b2[tid];
    for (int i = 0; i < MDIM; i++) c += m1[i] * w2[i * MDIM + tid];
    m2[tid] = c > 0.f ? c : 0.f;
    __syncthreads();
    float p = m2[tid] * w3[tid];
    for (int o = 32; o > 0; o >>= 1) p += __shfl_down(p, o, 64);
    if (tid == 0) out[b] = p + b3[0];
}

// ---------------- launch ----------------

extern "C" void kernel_launch(void* const* d_in, const int* in_sizes, int n_in,
                              void* d_out, int out_size, void* d_ws, size_t ws_size,
                              hipStream_t stream) {
    const float* x     = (const float*)d_in[0];
    const int*   ei    = (const int*)d_in[1];
    const int*   et    = (const int*)d_in[2];
    const int*   batch = (const int*)d_in[3];
    const float* W1    = (const float*)d_in[4];
    const float* root1 = (const float*)d_in[5];
    const float* b1    = (const float*)d_in[6];
    const float* W2    = (const float*)d_in[7];
    const float* root2 = (const float*)d_in[8];
    const float* b2    = (const float*)d_in[9];
    const float* W3    = (const float*)d_in[10];
    const float* root3 = (const float*)d_in[11];
    const float* b3    = (const float*)d_in[12];
    const float* ws_w  = (const float*)d_in[13];
    const float* ws_b  = (const float*)d_in[14];
    const float* m_w1  = (const float*)d_in[15];
    const float* m_b1  = (const float*)d_in[16];
    const float* m_w2  = (const float*)d_in[17];
    const float* m_b2  = (const float*)d_in[18];
    const float* m_w3  = (const float*)d_in[19];
    const float* m_b3  = (const float*)d_in[20];
    float* out = (float*)d_out;

    char* ws = (char*)d_ws;
    size_t o = 0;
    auto take = [&](size_t bytes) { size_t r = o; o = (o + bytes + 255) & ~(size_t)255; return r; };

    // ---- zeroed region (single memset span) ----
    size_t o_cnt_rn = take((size_t)NREL * NNODES * 4);
    size_t o_tcnt   = take(RP * 4);
    size_t o_tcur   = take(RP * 4);
    size_t o_ddeg   = take((size_t)NNODES * 4);
    size_t o_dcur   = take((size_t)NNODES * 4);
    size_t o_tnrows = take(MAXT * 4);
    size_t o_zero_end = o;
    // ---- rest ----
    size_t o_toff   = take((RP + 1) * 4);
    size_t o_doff   = take((size_t)(NNODES + 1) * 4);
    size_t o_esrc   = take((size_t)EPTOT * 4);
    size_t o_qp     = take((size_t)EPTOT * 4);
    size_t o_escale = take((size_t)EPTOT * 4);
    size_t o_trel   = take(MAXT * 4);
    size_t o_tstart = take(MAXT * 4);
    size_t o_wt1    = take((size_t)RP * HDIM * FDIM * 2);
    size_t o_wt2    = take((size_t)RP * HDIM * HDIM * 2);
    size_t o_wt3    = take((size_t)RP * HDIM * HDIM * 2);
    size_t o_x16    = take((size_t)NNODES * FDIM * 2);
    size_t o_h16    = take((size_t)NNODES * HDIM * 2);
    size_t o_gate   = take((size_t)NNODES * 4);
    size_t o_pool   = take((size_t)NGRAPH * HDIM * 4);
    size_t o_y16    = take((size_t)EPTOT * HDIM * 2);   // 102.4 MB

    int*      cnt_rn   = (int*)(ws + o_cnt_rn);
    int*      type_cnt = (int*)(ws + o_tcnt);
    int*      type_cur = (int*)(ws + o_tcur);
    int*      ddeg     = (int*)(ws + o_ddeg);
    int*      dst_cur  = (int*)(ws + o_dcur);
    int*      tnrows   = (int*)(ws + o_tnrows);
    int*      type_off = (int*)(ws + o_toff);
    int*      dst_off  = (int*)(ws + o_doff);
    int*      esrc     = (int*)(ws + o_esrc);
    int*      qp       = (int*)(ws + o_qp);
    float*    escale   = (float*)(ws + o_escale);
    int*      trel     = (int*)(ws + o_trel);
    int*      tstart   = (int*)(ws + o_tstart);
    _Float16* Wt1      = (_Float16*)(ws + o_wt1);
    _Float16* Wt2      = (_Float16*)(ws + o_wt2);
    _Float16* Wt3      = (_Float16*)(ws + o_wt3);
    _Float16* x16      = (_Float16*)(ws + o_x16);
    _Float16* h16      = (_Float16*)(ws + o_h16);
    float*    gate     = (float*)(ws + o_gate);
    float*    pooled   = (float*)(ws + o_pool);
    _Float16* Y16      = (_Float16*)(ws + o_y16);

    // Single memset covers cnt_rn..tile_nrows (contiguous by construction).
    hipMemsetAsync(ws + o_cnt_rn, 0, o_zero_end - o_cnt_rn, stream);

    count_kernel<<<(NEDGES + 255) / 256, 256, 0, stream>>>(ei, et, cnt_rn, type_cnt, ddeg);
    scan2_kernel<<<2, 256, 0, stream>>>(type_cnt, type_off, trel, tstart, tnrows, ddeg, dst_off);
    scatter_kernel<<<(EPTOT + 255) / 256, 256, 0, stream>>>(ei, et, cnt_rn, type_off, type_cur,
                                                            dst_off, dst_cur, esrc, qp, escale);
    prep_kernel<<<PREP_TOT, 256, 0, stream>>>(W1, root1, W2, root2, W3, root3, x,
                                              Wt1, Wt2, Wt3, x16);

    // Layer 1 (K=64)
    edge_gemm_kernel<FDIM><<<MAXT, 512, 0, stream>>>(x16, Wt1, esrc, escale,
                                                     trel, tstart, tnrows, Y16);
    reduce_kernel<<<NNODES / 4, 256, 0, stream>>>(Y16, dst_off, qp, b1, h16);

    // Layer 2 (K=256)
    edge_gemm_kernel<HDIM><<<MAXT, 512, 0, stream>>>(h16, Wt2, esrc, escale,
                                                     trel, tstart, tnrows, Y16);
    reduce_kernel<<<NNODES / 4, 256, 0, stream>>>(Y16, dst_off, qp, b2, h16);

    // Layer 3 (K=256)
    edge_gemm_kernel<HDIM><<<MAXT, 512, 0, stream>>>(h16, Wt3, esrc, escale,
                                                     trel, tstart, tnrows, Y16);
    reduce_kernel<<<NNODES / 4, 256, 0, stream>>>(Y16, dst_off, qp, b3, h16);

    gate_kernel<<<NNODES / 4, 256, 0, stream>>>(h16, ws_w, ws_b, gate);
    pool_kernel<<<NGRAPH, 256, 0, stream>>>(h16, gate, batch, pooled);
    head_kernel<<<NGRAPH, 64, 0, stream>>>(pooled, m_w1, m_b1, m_w2, m_b2, m_w3, m_b3, out);

    (void)in_sizes; (void)n_in; (void)out_size; (void)ws_size;
}